// Round 6
// baseline (147.928 us; speedup 1.0000x reference)
//
#include <hip/hip_runtime.h>
#include <hip/hip_bf16.h>

// TopoGraphLayer: B=1024, NJ=16, NW=2, NT=2, D=128, H=128
// R6: occupancy fix. R5 k_edge was 2 waves/SIMD (total regs ~150 incl unified
// AGPR) -> 60% idle. Now __launch_bounds__(512,4) caps at 128 regs -> 4
// waves/SIMD; u32-unpacked A-build; swapped-operand MFMA in proj/node for
// vectorized stores; k_proj grid 448; k_node ILP-unrolled.

using short4v = __attribute__((ext_vector_type(4))) short;
using short8 = __attribute__((ext_vector_type(8))) short;
using f32x4  = __attribute__((ext_vector_type(4))) float;
using u32x4  = __attribute__((ext_vector_type(4))) unsigned;

#define DEVI __device__ __forceinline__

DEVI float b2f(short s){
  unsigned u = ((unsigned)(unsigned short)s) << 16;
  float f; __builtin_memcpy(&f, &u, 4); return f;
}
DEVI float lo16f(unsigned w){ unsigned u = w << 16; float f; __builtin_memcpy(&f,&u,4); return f; }
DEVI float hi16f(unsigned w){ unsigned u = w & 0xffff0000u; float f; __builtin_memcpy(&f,&u,4); return f; }
DEVI short f2b(float f){
  __hip_bfloat16 h = __float2bfloat16(f);
  short s; __builtin_memcpy(&s, &h, 2); return s;
}
DEVI float ldflex(const void* p, long i, int bf){
  return bf ? b2f(((const short*)p)[i]) : ((const float*)p)[i];
}
DEVI f32x4 mfma16(short8 a, short8 b, f32x4 c){
  return __builtin_amdgcn_mfma_f32_16x16x32_bf16(a, b, c, 0, 0, 0);
}

// ---------------- ws byte offsets ----------------
constexpr size_t OF_MASKF  = 256;
constexpr size_t OF_INVCNT = 65792;
constexpr size_t OF_XJ     = 69888;
constexpr size_t OF_XW     = 4264192;
constexpr size_t OF_XT     = 4788480;
constexpr size_t OF_W1T    = 5312768;   // bf16 [7][128][256]
constexpr size_t OF_W2T    = 5771520;   // bf16 [7][128][128]
constexpr size_t OF_EB1F   = 6000896;
constexpr size_t OF_EB2F   = 6004480;
constexpr size_t OF_JW1T   = 6008064;   // bf16 [128][512]
constexpr size_t OF_JW2T   = 6139136;   // bf16 [128][128]
constexpr size_t OF_JB1F   = 6171904;
constexpr size_t OF_JB2F   = 6172416;
constexpr size_t OF_WTW1T  = 6172928;   // bf16 [2][128][384]
constexpr size_t OF_WTW2T  = 6369536;   // bf16 [2][128][128]
constexpr size_t OF_WTB1F  = 6435072;
constexpr size_t OF_WTB2F  = 6436096;
constexpr size_t OF_UV     = 6437120;   // bf16, 14,680,064 elems
constexpr size_t OF_POOL   = 65157376;  // bf16, 7,340,032 elems

// projection jobs: job = net*2 + half (half0=src gets bias). 256 rows/wg.
__constant__ long long PJ_OFF[14] = {0,2097152,4194304,6291456,6553600,8650752,
  8912896,9175040,11272192,11534336,11796480,12058624,14155776,14417920};
__constant__ int PJ_SRC[14] = {0,0,0,1,0,2,1,0,1,2,2,0,2,1}; // 0=J,1=W,2=T
__constant__ int PJ_CUM[15] = {0,64,128,192,200,264,272,280,344,352,360,368,432,440,448};
// edge nets, 256 edge-rows per wg
__constant__ int EN_CUM[8]  = {0,1024,1152,1280,1408,1424,1552,1568};
__constant__ int EN_LGNS[7] = {4,4,4,1,1,1,1};
__constant__ int EN_LGND[7] = {4,1,1,4,1,4,1};
__constant__ long long EN_POOL[7] = {0,2097152,4194304,6291456,6553600,6815744,7077888};
// transpose jobs
__constant__ int TJ_CUM[21] = {0,32,64,96,128,160,192,224,240,256,272,288,304,320,336,400,416,464,512,528,544};
__constant__ int TJ_SEL[20] = {0,0,0,0,0,0,0,1,1,1,1,1,1,1,2,3,4,4,5,5};
__constant__ int TJ_OFF[20] = {0,32768,65536,98304,131072,163840,196608,
                               0,16384,32768,49152,65536,81920,98304,
                               0,0,0,49152,0,16384};
__constant__ int TJ_R[20]   = {256,256,256,256,256,256,256,128,128,128,128,128,128,128,512,128,384,384,128,128};

// -------- probe: detect float dtype (f32 vs bf16) and mask format --------
__global__ __launch_bounds__(64) void k_probe(const void* jets, const void* mask, int* flags){
  int l = threadIdx.x;
  int extreme = 0;
  #pragma unroll
  for(int s=0;s<4;s++){
    unsigned short v = ((const unsigned short*)jets)[(l*4+s)*2];
    int e = (v>>7)&0xff;
    if(e<110||e>140) extreme++;
  }
  #pragma unroll
  for(int o=1;o<64;o<<=1) extreme += __shfl_xor(extreme, o);
  bool all01=true, allf32=true;
  #pragma unroll
  for(int s=0;s<4;s++){
    unsigned w = ((const unsigned*)mask)[l*4+s];
    if(w>1u) all01=false;
    if(w!=0u && w!=0x3F800000u) allf32=false;
  }
  bool allbfv=true; int evnz=0;
  #pragma unroll
  for(int s=0;s<8;s++){
    unsigned short v = ((const unsigned short*)mask)[l*8+s];
    if(v!=0&&v!=0x3F80) allbfv=false;
    if(((l*8+s)&1)==0 && v!=0) evnz++;
  }
  #pragma unroll
  for(int o=1;o<64;o<<=1) evnz += __shfl_xor(evnz, o);
  bool allb01=true;
  #pragma unroll
  for(int s=0;s<16;s++){ if(((const unsigned char*)mask)[l*16+s]>1) allb01=false; }
  int a01 = __all(all01), af32 = __all(allf32), abf = __all(allbfv), ab01 = __all(allb01);
  if(l==0){
    flags[0] = (extreme <= 32) ? 1 : 0;   // 1=bf16 inputs, 0=f32
    int fmt = 0;
    if(a01) fmt=0; else if(abf && evnz>0) fmt=2; else if(af32) fmt=3; else if(ab01) fmt=1;
    flags[1] = fmt;
  }
}

// -------- maskf + invcnt + biases (merged) --------
__global__ __launch_bounds__(256) void k_maskbias(const void* mask, const int* flags,
    float* maskf, float* invcnt,
    const void* eb1, const void* eb2, const void* jb1, const void* jb2,
    const void* wb1, const void* wb2,
    float* EB1F, float* EB2F, float* JB1F, float* JB2F, float* WTB1F, float* WTB2F){
  int bid = blockIdx.x;
  if(bid < 64){
    int t = bid*256 + threadIdx.x;  // 0..16383
    int fmt = flags[1];
    float m;
    if(fmt==0)      m = (((const int*)mask)[t]!=0) ? 1.f : 0.f;
    else if(fmt==1) m = (((const unsigned char*)mask)[t]!=0) ? 1.f : 0.f;
    else if(fmt==2) m = (b2f(((const short*)mask)[t])!=0.f) ? 1.f : 0.f;
    else            m = (((const float*)mask)[t]!=0.f) ? 1.f : 0.f;
    maskf[t] = m;
    float s = m;
    for(int o=1;o<16;o<<=1) s += __shfl_xor(s, o);
    if((t&15)==0) invcnt[t>>4] = 1.f / fmaxf(s, 1.f);
  } else {
    int id = (bid-64)*256 + threadIdx.x;
    int bf = flags[0];
    if(id<896)        EB1F[id]       = ldflex(eb1, id, bf);
    else if(id<1792)  EB2F[id-896]   = ldflex(eb2, id-896, bf);
    else if(id<1920)  JB1F[id-1792]  = ldflex(jb1, id-1792, bf);
    else if(id<2048)  JB2F[id-1920]  = ldflex(jb2, id-1920, bf);
    else if(id<2304)  WTB1F[id-2048] = ldflex(wb1, id-2048, bf);
    else if(id<2560)  WTB2F[id-2304] = ldflex(wb2, id-2304, bf);
  }
}

// -------- convert node inputs to canonical bf16 (x4 vectorized) --------
__global__ __launch_bounds__(256) void k_convx(const void* jets, const void* nw, const void* nt,
                                               const int* flags, short* XJ, short* XW, short* XT){
  long i = ((long)blockIdx.x*256 + threadIdx.x)*4;
  int bf = flags[0];
  const void* src; short* dst; long o;
  if(i < 2097152){ src=jets; dst=XJ; o=i; }
  else if(i < 2359296){ src=nw; dst=XW; o=i-2097152; }
  else { src=nt; dst=XT; o=i-2359296; }
  short4v r;
  if(bf){
    r = *(const short4v*)((const short*)src + o);
  } else {
    f32x4 v = *(const f32x4*)((const float*)src + o);
    #pragma unroll
    for(int e=0;e<4;e++) r[e] = f2b(v[e]);
  }
  *(short4v*)(dst + o) = r;
}

// -------- weight transpose via LDS 32x32 tiles --------
__global__ __launch_bounds__(256) void k_trans(const void* eW1, const void* eW2, const void* jW1,
    const void* jW2, const void* wW1, const void* wW2, const int* flags,
    short* W1T, short* W2T, short* JW1T, short* JW2T, short* WTW1T, short* WTW2T){
  __shared__ float tl[32][33];
  int tile = blockIdx.x; int job = 0;
  while(tile >= TJ_CUM[job+1]) job++;
  tile -= TJ_CUM[job];
  int sel = TJ_SEL[job]; long off = TJ_OFF[job]; int R = TJ_R[job];
  int bf = flags[0];
  const void* src = sel==0?eW1: sel==1?eW2: sel==2?jW1: sel==3?jW2: sel==4?wW1: wW2;
  short* dst = sel==0?W1T: sel==1?W2T: sel==2?JW1T: sel==3?JW2T: sel==4?WTW1T: WTW2T;
  int tr = (tile>>2)*32, tc = (tile&3)*32;
  int t = threadIdx.x, r = t>>3, c4 = (t&7)*4;
  #pragma unroll
  for(int j=0;j<4;j++) tl[r][c4+j] = ldflex(src, off + (long)(tr+r)*128 + tc + c4 + j, bf);
  __syncthreads();
  short4v o;
  #pragma unroll
  for(int j=0;j<4;j++) o[j] = f2b(tl[c4+j][r]);
  *(short4v*)(dst + off + (long)(tc+r)*R + tr + c4) = o;
}

// -------- projections: UVb[row][128] bf16 = X @ W1half (+b1 on src half) --------
// 512 thr = 8 waves; wave = 16 rows x 64 cols; 4 chunks; 256 rows/wg.
// Swapped MFMA: lane holds 4 consecutive cols of one row -> short4 store.
__global__ __launch_bounds__(512, 4) void k_proj(const short* XJ, const short* XW, const short* XT,
                                                 const short* W1T, const float* EB1F, short* UVb){
  int bid = blockIdx.x;
  int job = 0;
  while(bid >= PJ_CUM[job+1]) job++;
  long row0 = (long)(bid - PJ_CUM[job]) * 256;
  const short* X = (PJ_SRC[job]==0) ? XJ : ((PJ_SRC[job]==1) ? XW : XT);
  const short* Wb = W1T + (long)(job>>1)*32768 + (job&1)*128;  // rows stride 256
  short* out = UVb + PJ_OFF[job];
  int net = job>>1; bool addb = (job&1)==0;
  int t = threadIdx.x, lane = t & 63, wv = t >> 6;
  int rb = wv >> 1, ch = (wv & 1)*64;
  int cl = lane & 15, kh = lane >> 4;
  short8 b[4][4];
  f32x4 biasv[4];
  #pragma unroll
  for(int nt=0;nt<4;nt++){
    #pragma unroll
    for(int ks=0;ks<4;ks++)
      b[nt][ks] = *(const short8*)(Wb + (ch + nt*16 + cl)*256 + ks*32 + kh*8);
    if(addb) biasv[nt] = *(const f32x4*)(EB1F + net*128 + ch + nt*16 + kh*4);
    else     biasv[nt] = f32x4{0.f,0.f,0.f,0.f};
  }
  #pragma unroll 1
  for(int c=0;c<4;c++){
    long T0 = row0 + c*64 + rb*16;
    short8 a[4];
    #pragma unroll
    for(int ks=0;ks<4;ks++)
      a[ks] = *(const short8*)(X + (T0 + cl)*128 + ks*32 + kh*8);
    f32x4 acc[4] = {};
    #pragma unroll
    for(int ks=0;ks<4;ks++)
      #pragma unroll
      for(int nt=0;nt<4;nt++)
        acc[nt] = mfma16(b[nt][ks], a[ks], acc[nt]);   // swapped: D[wcol][xrow]
    #pragma unroll
    for(int nt=0;nt<4;nt++){
      short4v sv;
      #pragma unroll
      for(int r=0;r<4;r++) sv[r] = f2b(acc[nt][r] + biasv[nt][r]);
      *(short4v*)(out + (T0 + cl)*128 + ch + nt*16 + kh*4) = sv;
    }
  }
}

// -------- edge layer2 + pooling: 256 rows/wg, 4 waves/SIMD, u32 A-build --------
__global__ __launch_bounds__(512, 4) void k_edge(const short* UVb, const short* W2T, const float* EB2F,
                                                 const float* maskf, const float* invcnt, short* POOL){
  int bid = blockIdx.x;
  int net = 0;
  while(bid >= EN_CUM[net+1]) net++;
  int idx = bid - EN_CUM[net];
  int lgNs = EN_LGNS[net], lgNd = EN_LGND[net];
  int masked = (lgNd == 4);
  long R0 = (long)idx * 256;
  const short* U = UVb + PJ_OFF[2*net];
  const short* V = UVb + PJ_OFF[2*net+1];
  const short* Wb = W2T + (long)net*16384;
  short* pool = POOL + EN_POOL[net];
  int t = threadIdx.x, lane = t & 63, wv = t >> 6;
  int rb = wv >> 1, ch = (wv & 1)*64;
  int cl = lane & 15, kh = lane >> 4;
  short8 b[4][4];
  float bias[4];
  #pragma unroll
  for(int nt=0;nt<4;nt++){
    #pragma unroll
    for(int ks=0;ks<4;ks++)
      b[nt][ks] = *(const short8*)(Wb + (ch + nt*16 + cl)*128 + ks*32 + kh*8);
    bias[nt] = EB2F[net*128 + ch + nt*16 + cl];
  }
  #pragma unroll 1
  for(int c=0;c<4;c++){
    long T0 = R0 + c*64 + rb*16;
    long R = T0 + cl;
    long urow = R >> lgNd;
    long vrow = ((R >> (lgNs+lgNd)) << lgNd) | (R & ((1<<lgNd)-1));
    u32x4 uw[4], vw[4];
    #pragma unroll
    for(int ks=0;ks<4;ks++){
      uw[ks] = *(const u32x4*)(U + urow*128 + ks*32 + kh*8);
      vw[ks] = *(const u32x4*)(V + vrow*128 + ks*32 + kh*8);
    }
    f32x4 acc[4] = {};
    #pragma unroll
    for(int ks=0;ks<4;ks++){
      short8 a;
      #pragma unroll
      for(int p=0;p<4;p++){
        float al = fmaxf(lo16f(uw[ks][p]) + lo16f(vw[ks][p]), 0.f);
        float ah = fmaxf(hi16f(uw[ks][p]) + hi16f(vw[ks][p]), 0.f);
        a[2*p]   = f2b(al);
        a[2*p+1] = f2b(ah);
      }
      #pragma unroll
      for(int nt=0;nt<4;nt++)
        acc[nt] = mfma16(a, b[nt][ks], acc[nt]);   // D[edge-row][wcol]
    }
    if(masked){
      long bb = T0 >> (lgNs + 4);
      float ic = invcnt[bb];
      float wr[4];
      #pragma unroll
      for(int r=0;r<4;r++)
        wr[r] = maskf[bb*16 + ((T0 + kh*4 + r) & 15)] * ic;
      #pragma unroll
      for(int nt=0;nt<4;nt++){
        int col = ch + nt*16 + cl;
        float s = fmaxf(acc[nt][0]+bias[nt],0.f)*wr[0]
                + fmaxf(acc[nt][1]+bias[nt],0.f)*wr[1]
                + fmaxf(acc[nt][2]+bias[nt],0.f)*wr[2]
                + fmaxf(acc[nt][3]+bias[nt],0.f)*wr[3];
        s += __shfl_xor(s, 16);
        s += __shfl_xor(s, 32);
        if(lane < 16)
          pool[(T0 >> 4)*128 + col] = f2b(s);
      }
    } else {
      #pragma unroll
      for(int nt=0;nt<4;nt++){
        int col = ch + nt*16 + cl;
        float v0 = fmaxf(acc[nt][0]+bias[nt],0.f);
        float v1 = fmaxf(acc[nt][1]+bias[nt],0.f);
        float v2 = fmaxf(acc[nt][2]+bias[nt],0.f);
        float v3 = fmaxf(acc[nt][3]+bias[nt],0.f);
        long g = (T0 + kh*4) >> 1;
        pool[g*128 + col]     = f2b((v0+v1)*0.5f);
        pool[(g+1)*128 + col] = f2b((v2+v3)*0.5f);
      }
    }
  }
}

// -------- node nets: 64 rows/wg (4 waves x 16 rows x 128 cols), swapped MFMA --------
__global__ __launch_bounds__(256) void k_node(const short* XJ, const short* XW, const short* XT,
    const short* POOL, const short* JW1T, const short* JW2T, const float* JB1F, const float* JB2F,
    const short* WTW1T, const short* WTW2T, const float* WTB1F, const float* WTB2F,
    const float* maskf, const int* flags, void* out){
  __shared__ short hs[8192];  // 64 x 128 bf16, XOR-swizzled
  int bid = blockIdx.x;
  int net; long row0;
  if(bid < 256){ net=0; row0=(long)bid*64; }
  else if(bid < 288){ net=1; row0=(long)(bid-256)*64; }
  else { net=2; row0=(long)(bid-288)*64; }
  int NQ = (net==0) ? 4 : 3;
  int K1 = NQ*128;
  const short* X = (net==0) ? XJ : ((net==1) ? XW : XT);
  const short *P1, *P2, *P3 = nullptr;
  if(net==0){ P1=POOL; P2=POOL+2097152; P3=POOL+4194304; }
  else if(net==1){ P1=POOL+6291456; P2=POOL+6553600; }
  else { P1=POOL+6815744; P2=POOL+7077888; }
  const short* W1 = (net==0) ? JW1T : WTW1T + (long)(net-1)*49152;
  const short* W2 = (net==0) ? JW2T : WTW2T + (long)(net-1)*16384;
  const float* B1 = (net==0) ? JB1F : WTB1F + (net-1)*128;
  const float* B2 = (net==0) ? JB2F : WTB2F + (net-1)*128;
  int t = threadIdx.x, lane = t & 63, wv = t >> 6;
  int cl = lane & 15, kh = lane >> 4;
  int rl = wv*16 + cl;
  long xrow = row0 + rl;
  f32x4 acc[8] = {};
  #pragma unroll
  for(int q=0;q<4;q++){
    if(q < NQ){
      const short* SA = (q==0)?X:((q==1)?P1:((q==2)?P2:P3));
      #pragma unroll
      for(int ks=0;ks<4;ks++){
        short8 a = *(const short8*)(SA + xrow*128 + ks*32 + kh*8);
        #pragma unroll
        for(int nt=0;nt<8;nt++){
          short8 bb = *(const short8*)(W1 + (long)(nt*16 + cl)*K1 + q*128 + ks*32 + kh*8);
          acc[nt] = mfma16(bb, a, acc[nt]);   // D[w1col][xrow]
        }
      }
    }
  }
  #pragma unroll
  for(int nt=0;nt<8;nt++){
    f32x4 bv = *(const f32x4*)(B1 + nt*16 + kh*4);
    short4v sv;
    #pragma unroll
    for(int r=0;r<4;r++) sv[r] = f2b(fmaxf(acc[nt][r] + bv[r], 0.f));
    *(short4v*)((char*)hs + ((rl*256 + (nt*16 + kh*4)*2) ^ ((rl&7)<<4))) = sv;
  }
  __syncthreads();
  f32x4 acc2[8] = {};
  #pragma unroll
  for(int k0=0;k0<4;k0++){
    short8 a = *(const short8*)((const char*)hs + ((rl*256 + (k0*32 + kh*8)*2) ^ ((rl&7)<<4)));
    #pragma unroll
    for(int nt=0;nt<8;nt++){
      short8 bb = *(const short8*)(W2 + (nt*16 + cl)*128 + k0*32 + kh*8);
      acc2[nt] = mfma16(bb, a, acc2[nt]);   // D[w2col][xrow]
    }
  }
  int obf = flags[0];
  long grow = row0 + rl;
  long bbn, node; float mscale = 1.f;
  if(net==0){ bbn = grow>>4; node = grow&15; mscale = maskf[grow]; }
  else if(net==1){ bbn = grow>>1; node = 16 + (grow&1); }
  else { bbn = grow>>1; node = 18 + (grow&1); }
  long obase = (bbn*20 + node)*128;
  #pragma unroll
  for(int nt=0;nt<8;nt++){
    f32x4 bv = *(const f32x4*)(B2 + nt*16 + kh*4);
    f32x4 fv;
    #pragma unroll
    for(int r=0;r<4;r++) fv[r] = fmaxf(acc2[nt][r] + bv[r], 0.f) * mscale;
    if(obf){
      short4v sv;
      #pragma unroll
      for(int r=0;r<4;r++) sv[r] = f2b(fv[r]);
      *(short4v*)((short*)out + obase + nt*16 + kh*4) = sv;
    } else {
      *(f32x4*)((float*)out + obase + nt*16 + kh*4) = fv;
    }
  }
}

extern "C" void kernel_launch(void* const* d_in, const int* in_sizes, int n_in,
                              void* d_out, int out_size, void* d_ws, size_t ws_size,
                              hipStream_t stream){
  char* ws = (char*)d_ws;
  int*   flags  = (int*)ws;
  float* maskf  = (float*)(ws + OF_MASKF);
  float* invcnt = (float*)(ws + OF_INVCNT);
  short* XJ     = (short*)(ws + OF_XJ);
  short* XW     = (short*)(ws + OF_XW);
  short* XT     = (short*)(ws + OF_XT);
  short* W1T    = (short*)(ws + OF_W1T);
  short* W2T    = (short*)(ws + OF_W2T);
  float* EB1F   = (float*)(ws + OF_EB1F);
  float* EB2F   = (float*)(ws + OF_EB2F);
  short* JW1T   = (short*)(ws + OF_JW1T);
  short* JW2T   = (short*)(ws + OF_JW2T);
  float* JB1F   = (float*)(ws + OF_JB1F);
  float* JB2F   = (float*)(ws + OF_JB2F);
  short* WTW1T  = (short*)(ws + OF_WTW1T);
  short* WTW2T  = (short*)(ws + OF_WTW2T);
  float* WTB1F  = (float*)(ws + OF_WTB1F);
  float* WTB2F  = (float*)(ws + OF_WTB2F);
  short* UVb    = (short*)(ws + OF_UV);
  short* POOL   = (short*)(ws + OF_POOL);

  k_probe<<<1, 64, 0, stream>>>(d_in[0], d_in[3], flags);
  k_maskbias<<<74, 256, 0, stream>>>(d_in[3], flags, maskf, invcnt,
                                     d_in[5], d_in[7], d_in[9], d_in[11], d_in[13], d_in[15],
                                     EB1F, EB2F, JB1F, JB2F, WTB1F, WTB2F);
  k_convx<<<2560, 256, 0, stream>>>(d_in[0], d_in[1], d_in[2], flags, XJ, XW, XT);
  k_trans<<<544, 256, 0, stream>>>(d_in[4], d_in[6], d_in[8], d_in[10], d_in[12], d_in[14],
                                   flags, W1T, W2T, JW1T, JW2T, WTW1T, WTW2T);
  k_proj <<<448, 512, 0, stream>>>(XJ, XW, XT, W1T, EB1F, UVb);
  k_edge <<<1568, 512, 0, stream>>>(UVb, W2T, EB2F, maskf, invcnt, POOL);
  k_node <<<320, 256, 0, stream>>>(XJ, XW, XT, POOL, JW1T, JW2T, JB1F, JB2F,
                                   WTW1T, WTW2T, WTB1F, WTB2F, maskf, flags, d_out);
}